// Round 10
// baseline (353.750 us; speedup 1.0000x reference)
//
#include <hip/hip_runtime.h>

#define BS 65536
#define DIM 64
#define SD 1024
#define NTHREADS 512
#define NBLK 1024         // 8 waves/block = 4 pairs x 16 rows; pair splits 1024 cbs in half
#define LOG2E 1.44269504f
#define LN2   0.69314718f

// workspace layout (bytes)
#define WS_CBB   0        // [1024][64] bf16 row-major codebook (128 KB)
#define WS_CBT   131072   // [64][1024] bf16 transposed codebook (128 KB)
#define WS_C2    262144   // [1024] f32
#define WS_AVG   266240   // [1024] f32 accumulator (zeroed by prep)
#define WS_APART 270336   // [1024][1024] f16 per-block avg partials (2 MB)
#define WS_LPART 2367488  // [1024] f32 per-block loss partials

typedef __attribute__((ext_vector_type(8))) short bf16x8;
typedef __attribute__((ext_vector_type(4))) float f32x4;
typedef __attribute__((ext_vector_type(2))) _Float16 f16x2;

__device__ __forceinline__ unsigned short f2bf(float f) {
  union { float f; unsigned int u; } v; v.f = f;
  unsigned int r = v.u + 0x7fffu + ((v.u >> 16) & 1u);
  return (unsigned short)(r >> 16);
}
__device__ __forceinline__ unsigned cvtpk(float a, float b) {  // lo=bf16(a), hi=bf16(b)
  unsigned r;
  asm("v_cvt_pk_bf16_f32 %0, %1, %2" : "=v"(r) : "v"(a), "v"(b));
  return r;
}
__device__ __forceinline__ float bflo(unsigned v) {
  union { unsigned u; float f; } x; x.u = v << 16; return x.f;
}
__device__ __forceinline__ float bfhi(unsigned v) {
  union { unsigned u; float f; } x; x.u = v & 0xffff0000u; return x.f;
}
__device__ __forceinline__ float wsum64(float v) {
  #pragma unroll
  for (int m = 1; m < 64; m <<= 1) v += __shfl_xor(v, m);
  return v;
}
__device__ __forceinline__ bf16x8 pack8(float4 a, float4 b) {
  bf16x8 r;
  r[0]=(short)f2bf(a.x); r[1]=(short)f2bf(a.y); r[2]=(short)f2bf(a.z); r[3]=(short)f2bf(a.w);
  r[4]=(short)f2bf(b.x); r[5]=(short)f2bf(b.y); r[6]=(short)f2bf(b.z); r[7]=(short)f2bf(b.w);
  return r;
}

// ---------------- prep: bf16 codebook (row-major + transposed), c2, zero avgg ----------------
__global__ __launch_bounds__(256) void gvq_prep(const float* __restrict__ cb, char* __restrict__ ws) {
  int gid = blockIdx.x * 256 + threadIdx.x;   // 0..16383
  int j = gid >> 4, dg = gid & 15;
  float4 v = *(const float4*)(cb + j * DIM + dg * 4);
  float s = v.x*v.x + v.y*v.y + v.z*v.z + v.w*v.w;
  s += __shfl_xor(s, 1); s += __shfl_xor(s, 2); s += __shfl_xor(s, 4); s += __shfl_xor(s, 8);
  unsigned short b0 = f2bf(v.x), b1 = f2bf(v.y), b2 = f2bf(v.z), b3 = f2bf(v.w);
  uint2 pk;
  pk.x = (unsigned)b0 | ((unsigned)b1 << 16);
  pk.y = (unsigned)b2 | ((unsigned)b3 << 16);
  *(uint2*)(ws + WS_CBB + j * 128 + dg * 8) = pk;
  unsigned short* tb = (unsigned short*)(ws + WS_CBT);
  int d = dg * 4;
  tb[(d + 0) * 1024 + j] = b0; tb[(d + 1) * 1024 + j] = b1;
  tb[(d + 2) * 1024 + j] = b2; tb[(d + 3) * 1024 + j] = b3;
  if (dg == 0) ((float*)(ws + WS_C2))[j] = s;
  if (gid < SD) ((float*)(ws + WS_AVG))[gid] = 0.f;
}

// ---------------- main: 1024 blocks x 4 pairs; each wave = 16 rows x 512 cbs ----------------
__global__ __launch_bounds__(NTHREADS, 8) void gvq_main(
    const float* __restrict__ z, const float* __restrict__ pq,
    const float* __restrict__ u, char* __restrict__ ws,
    float* __restrict__ out)
{
  __shared__ float pavw[4][1024];        // per-pair avg-prob accumulator
  __shared__ char  eyb_s[8][1280];       // per-wave ey bounce (rows stride 80)
  __shared__ char  zqm_s[4][2560];       // per-pair zq partial, lane stride 40
  __shared__ float stm[4][2][16];
  __shared__ float stz[4][2][16];
  __shared__ float ste[4][2][16];
  __shared__ float zy2[4][2][16];
  __shared__ float wred[8];

  const int t    = threadIdx.x;
  const int lane = t & 63;
  const int wave = t >> 6;
  const int l15  = lane & 15;
  const int g    = lane >> 4;
  const int pair = wave >> 1;
  const int h    = wave & 1;
  const int r0   = blockIdx.x * 64 + pair * 16;
  const int ttB  = h * 32;

  const char*  cbbp = ws + WS_CBB;
  const char*  cbtp = ws + WS_CBT;
  const float* c2p  = (const float*)(ws + WS_C2);
  _Float16* apart = (_Float16*)(ws + WS_APART);
  float* lpart = (float*)(ws + WS_LPART);

  const float weight = 0.5f / fmaxf(pq[0], 1e-10f);
  const float w2  = weight * LOG2E;
  const float w22 = 2.f * w2;

  {
    float* pz = &pavw[0][0];
    #pragma unroll
    for (int i = 0; i < 8; ++i) pz[t + 512 * i] = 0.f;
  }

  // ---- z fragment (B-operand layout) + z2 ----
  const float* zr = z + (size_t)(r0 + l15) * DIM + g * 8;
  float4 za = *(const float4*)(zr);
  float4 zb = *(const float4*)(zr + 4);
  float4 zc = *(const float4*)(zr + 32);
  float4 zd = *(const float4*)(zr + 36);
  bf16x8 zf0 = pack8(za, zb);
  bf16x8 zf1 = pack8(zc, zd);
  float zsq = za.x*za.x+za.y*za.y+za.z*za.z+za.w*za.w
            + zb.x*zb.x+zb.y*zb.y+zb.z*zb.z+zb.w*zb.w
            + zc.x*zc.x+zc.y*zc.y+zc.z*zc.z+zc.w*zc.w
            + zd.x*zd.x+zd.y*zd.y+zd.z*zd.z+zd.w*zd.w;
  zsq += __shfl_xor(zsq, 16); zsq += __shfl_xor(zsq, 32);
  const float zpart = w2 * zsq;

  // ---- pass A: row max (no serial rescale chain) ----
  float m0 = -3e38f, m1 = -3e38f, m2 = -3e38f, m3 = -3e38f;
  for (int tt = ttB; tt < ttB + 32; ++tt) {
    const char* cp = cbbp + (tt * 16 + l15) * 128 + g * 16;
    bf16x8 cf0 = *(const bf16x8*)(cp);
    bf16x8 cf1 = *(const bf16x8*)(cp + 64);
    f32x4 acc = {0.f, 0.f, 0.f, 0.f};
    acc = __builtin_amdgcn_mfma_f32_16x16x32_bf16(cf0, zf0, acc, 0, 0, 0);
    acc = __builtin_amdgcn_mfma_f32_16x16x32_bf16(cf1, zf1, acc, 0, 0, 0);
    float4 c2v = *(const float4*)(c2p + tt * 16 + g * 4);
    m0 = fmaxf(m0, fmaf(w22, acc[0], -(zpart + w2 * c2v.x)));
    m1 = fmaxf(m1, fmaf(w22, acc[1], -(zpart + w2 * c2v.y)));
    m2 = fmaxf(m2, fmaf(w22, acc[2], -(zpart + w2 * c2v.z)));
    m3 = fmaxf(m3, fmaf(w22, acc[3], -(zpart + w2 * c2v.w)));
  }
  float m = fmaxf(fmaxf(m0, m1), fmaxf(m2, m3));
  m = fmaxf(m, __shfl_xor(m, 16)); m = fmaxf(m, __shfl_xor(m, 32));
  if (lane < 16) stm[pair][h][lane] = m;
  __syncthreads();
  m = fmaxf(stm[pair][0][l15], stm[pair][1][l15]);

  // ---- pass B: Zs, E1 with final m ----
  float Zs0 = 0.f, Zs1 = 0.f, E10 = 0.f, E11 = 0.f;
  for (int tt = ttB; tt < ttB + 32; ++tt) {
    const char* cp = cbbp + (tt * 16 + l15) * 128 + g * 16;
    bf16x8 cf0 = *(const bf16x8*)(cp);
    bf16x8 cf1 = *(const bf16x8*)(cp + 64);
    f32x4 acc = {0.f, 0.f, 0.f, 0.f};
    acc = __builtin_amdgcn_mfma_f32_16x16x32_bf16(cf0, zf0, acc, 0, 0, 0);
    acc = __builtin_amdgcn_mfma_f32_16x16x32_bf16(cf1, zf1, acc, 0, 0, 0);
    float4 c2v = *(const float4*)(c2p + tt * 16 + g * 4);
    float d0 = fmaf(w22, acc[0], -(zpart + w2 * c2v.x)) - m;
    float d1 = fmaf(w22, acc[1], -(zpart + w2 * c2v.y)) - m;
    float d2 = fmaf(w22, acc[2], -(zpart + w2 * c2v.z)) - m;
    float d3 = fmaf(w22, acc[3], -(zpart + w2 * c2v.w)) - m;
    float e0 = __builtin_amdgcn_exp2f(d0), e1 = __builtin_amdgcn_exp2f(d1);
    float e2 = __builtin_amdgcn_exp2f(d2), e3 = __builtin_amdgcn_exp2f(d3);
    Zs0 += e0 + e2; Zs1 += e1 + e3;
    E10 += e0 * d0 + e2 * d2; E11 += e1 * d1 + e3 * d3;
  }
  float Zs = Zs0 + Zs1, E1 = E10 + E11;
  Zs += __shfl_xor(Zs, 16); E1 += __shfl_xor(E1, 16);
  Zs += __shfl_xor(Zs, 32); E1 += __shfl_xor(E1, 32);
  if (lane < 16) { stz[pair][h][lane] = Zs; ste[pair][h][lane] = E1; }
  __syncthreads();
  Zs = stz[pair][0][l15] + stz[pair][1][l15];
  E1 = ste[pair][0][l15] + ste[pair][1][l15];
  const float invZ = 1.f / Zs;
  float kd_acc = (h == 0 && g == 0)
               ? LN2 * (E1 * invZ - __builtin_amdgcn_logf(Zs)) : 0.f;

  // ---- pass C: recompute e; pav quad-reduce + ds_add; gumbel ey -> PV ----
  f32x4 q0 = {0.f,0.f,0.f,0.f}, q1 = {0.f,0.f,0.f,0.f};
  f32x4 q2 = {0.f,0.f,0.f,0.f}, q3 = {0.f,0.f,0.f,0.f};
  float Zy = 0.f;
  const float* up = u + (size_t)(r0 + l15) * SD;
  char* eyb = eyb_s[wave];

  for (int kt = h * 16; kt < h * 16 + 16; ++kt) {
    #pragma unroll
    for (int T = 0; T < 2; ++T) {
      const int tt = kt * 2 + T;
      const char* cp = cbbp + (tt * 16 + l15) * 128 + g * 16;
      bf16x8 cf0 = *(const bf16x8*)(cp);
      bf16x8 cf1 = *(const bf16x8*)(cp + 64);
      f32x4 acc = {0.f, 0.f, 0.f, 0.f};
      acc = __builtin_amdgcn_mfma_f32_16x16x32_bf16(cf0, zf0, acc, 0, 0, 0);
      acc = __builtin_amdgcn_mfma_f32_16x16x32_bf16(cf1, zf1, acc, 0, 0, 0);
      float4 c2v = *(const float4*)(c2p + tt * 16 + g * 4);
      float4 u4  = *(const float4*)(up + tt * 16 + g * 4);
      float d0 = fmaf(w22, acc[0], -(zpart + w2 * c2v.x)) - m;
      float d1 = fmaf(w22, acc[1], -(zpart + w2 * c2v.y)) - m;
      float d2 = fmaf(w22, acc[2], -(zpart + w2 * c2v.z)) - m;
      float d3 = fmaf(w22, acc[3], -(zpart + w2 * c2v.w)) - m;
      float e0 = __builtin_amdgcn_exp2f(d0), e1 = __builtin_amdgcn_exp2f(d1);
      float e2 = __builtin_amdgcn_exp2f(d2), e3 = __builtin_amdgcn_exp2f(d3);
      float p0 = e0 * invZ, p1 = e1 * invZ, p2 = e2 * invZ, p3 = e3 * invZ;
      p0 += __shfl_xor(p0, 1); p1 += __shfl_xor(p1, 1);
      p2 += __shfl_xor(p2, 1); p3 += __shfl_xor(p3, 1);
      p0 += __shfl_xor(p0, 2); p1 += __shfl_xor(p1, 2);
      p2 += __shfl_xor(p2, 2); p3 += __shfl_xor(p3, 2);
      if ((l15 & 3) == 0) {
        float* pp = &pavw[pair][tt * 16 + g * 4];
        atomicAdd(pp + 0, p0); atomicAdd(pp + 1, p1);
        atomicAdd(pp + 2, p2); atomicAdd(pp + 3, p3);
      }
      float B0 = fmaf(-LN2, __builtin_amdgcn_logf(u4.x + 1e-10f), 1e-10f);
      float B1 = fmaf(-LN2, __builtin_amdgcn_logf(u4.y + 1e-10f), 1e-10f);
      float B2 = fmaf(-LN2, __builtin_amdgcn_logf(u4.z + 1e-10f), 1e-10f);
      float B3 = fmaf(-LN2, __builtin_amdgcn_logf(u4.w + 1e-10f), 1e-10f);
      float y0 = e0 * (5.9604645e-8f * __builtin_amdgcn_rcpf(B0));
      float y1 = e1 * (5.9604645e-8f * __builtin_amdgcn_rcpf(B1));
      float y2 = e2 * (5.9604645e-8f * __builtin_amdgcn_rcpf(B2));
      float y3 = e3 * (5.9604645e-8f * __builtin_amdgcn_rcpf(B3));
      Zy += (y0 + y1) + (y2 + y3);
      uint2 pk;
      pk.x = cvtpk(y0, y1);
      pk.y = cvtpk(y2, y3);
      *(uint2*)(eyb + l15 * 80 + T * 32 + g * 8) = pk;
    }
    bf16x8 ef = *(const bf16x8*)(eyb + l15 * 80 + g * 16);
    const char* bp = cbtp + l15 * 2048 + kt * 64 + g * 16;
    q0 = __builtin_amdgcn_mfma_f32_16x16x32_bf16(ef, *(const bf16x8*)(bp),             q0, 0, 0, 0);
    q1 = __builtin_amdgcn_mfma_f32_16x16x32_bf16(ef, *(const bf16x8*)(bp + 16 * 2048), q1, 0, 0, 0);
    q2 = __builtin_amdgcn_mfma_f32_16x16x32_bf16(ef, *(const bf16x8*)(bp + 32 * 2048), q2, 0, 0, 0);
    q3 = __builtin_amdgcn_mfma_f32_16x16x32_bf16(ef, *(const bf16x8*)(bp + 48 * 2048), q3, 0, 0, 0);
  }

  // ---- pair merge: Zy + zq partial ----
  Zy += __shfl_xor(Zy, 16); Zy += __shfl_xor(Zy, 32);
  if (lane < 16) zy2[pair][h][lane] = Zy;
  if (h == 1) {
    char* zq = &zqm_s[pair][lane * 40];
    *(uint2*)(zq +  0) = (uint2){cvtpk(q0[0], q0[1]), cvtpk(q0[2], q0[3])};
    *(uint2*)(zq +  8) = (uint2){cvtpk(q1[0], q1[1]), cvtpk(q1[2], q1[3])};
    *(uint2*)(zq + 16) = (uint2){cvtpk(q2[0], q2[1]), cvtpk(q2[2], q2[3])};
    *(uint2*)(zq + 24) = (uint2){cvtpk(q3[0], q3[1]), cvtpk(q3[2], q3[3])};
  }
  __syncthreads();

  float kc_acc = 0.f;
  if (h == 0) {
    const char* zq = &zqm_s[pair][lane * 40];
    float iy0 = 1.f / (zy2[pair][0][4 * g + 0] + zy2[pair][1][4 * g + 0]);
    float iy1 = 1.f / (zy2[pair][0][4 * g + 1] + zy2[pair][1][4 * g + 1]);
    float iy2 = 1.f / (zy2[pair][0][4 * g + 2] + zy2[pair][1][4 * g + 2]);
    float iy3 = 1.f / (zy2[pair][0][4 * g + 3] + zy2[pair][1][4 * g + 3]);
#define FIN(Q, DT) do { \
    uint2 v = *(const uint2*)(zq + 8 * (DT)); \
    size_t base = (size_t)(r0 + 4 * g) * DIM + (DT) * 16 + l15; \
    float s0 = (Q[0] + bflo(v.x)) * iy0, s1 = (Q[1] + bfhi(v.x)) * iy1; \
    float s2 = (Q[2] + bflo(v.y)) * iy2, s3 = (Q[3] + bfhi(v.y)) * iy3; \
    out[base] = s0; out[base + DIM] = s1; \
    out[base + 2 * DIM] = s2; out[base + 3 * DIM] = s3; \
    float dz0 = z[base] - s0, dz1 = z[base + DIM] - s1; \
    float dz2 = z[base + 2 * DIM] - s2, dz3 = z[base + 3 * DIM] - s3; \
    kc_acc += (dz0 * dz0 + dz1 * dz1) + (dz2 * dz2 + dz3 * dz3); \
  } while (0)
    FIN(q0, 0); FIN(q1, 1); FIN(q2, 2); FIN(q3, 3);
#undef FIN
  }
  float kcs = wsum64(kc_acc);
  float kds = wsum64(kd_acc);
  if (lane == 0) wred[wave] = kds + weight * kcs;
  __syncthreads();

  // ---- flush: per-block partials ----
  {
    float s0 = pavw[0][t] + pavw[1][t] + pavw[2][t] + pavw[3][t];
    float s1 = pavw[0][t + 512] + pavw[1][t + 512] + pavw[2][t + 512] + pavw[3][t + 512];
    apart[(size_t)blockIdx.x * 1024 + t]       = (_Float16)s0;
    apart[(size_t)blockIdx.x * 1024 + t + 512] = (_Float16)s1;
    if (t == 0) {
      float L = 0.f;
      #pragma unroll
      for (int w = 0; w < 8; ++w) L += wred[w];
      lpart[blockIdx.x] = L;
    }
  }
}

// ---------------- reduce avg partials: 32 blocks x 32 rows each ----------------
__global__ __launch_bounds__(512) void gvq_red(char* __restrict__ ws) {
  const _Float16* apart = (const _Float16*)(ws + WS_APART);
  float* avgg           = (float*)(ws + WS_AVG);
  int bb = blockIdx.x, t = threadIdx.x;
  float s0 = 0.f, s1 = 0.f;
  #pragma unroll
  for (int r = 0; r < 32; ++r) {
    f16x2 v = *(const f16x2*)(apart + (size_t)(bb * 32 + r) * 1024 + t * 2);
    s0 += (float)v[0]; s1 += (float)v[1];
  }
  atomicAdd(&avgg[t * 2], s0);
  atomicAdd(&avgg[t * 2 + 1], s1);
}

// ---------------- final: loss + perplexity ----------------
__global__ __launch_bounds__(256) void gvq_final(const char* __restrict__ ws, float* __restrict__ out) {
  const float* avgg  = (const float*)(ws + WS_AVG);
  const float* lpart = (const float*)(ws + WS_LPART);
  int t = threadIdx.x;
  float s = 0.f;
  #pragma unroll
  for (int i = t; i < SD; i += 256) {
    float a = avgg[i] * (1.f / 65536.f);
    s += a * logf(a + 1e-7f);
  }
  float lp = lpart[t] + lpart[t + 256] + lpart[t + 512] + lpart[t + 768];
  s = wsum64(s); lp = wsum64(lp);
  __shared__ float ws1[4], ws2[4];
  if ((t & 63) == 0) { ws1[t >> 6] = s; ws2[t >> 6] = lp; }
  __syncthreads();
  if (t == 0) {
    float tot = ws1[0] + ws1[1] + ws1[2] + ws1[3];
    float L   = ws2[0] + ws2[1] + ws2[2] + ws2[3];
    out[(size_t)BS * DIM]     = L * (1.f / 65536.f);
    out[(size_t)BS * DIM + 1] = expf(-tot);
  }
}

extern "C" void kernel_launch(void* const* d_in, const int* in_sizes, int n_in,
                              void* d_out, int out_size, void* d_ws, size_t ws_size,
                              hipStream_t stream) {
  (void)in_sizes; (void)n_in; (void)out_size; (void)ws_size;
  const float* z  = (const float*)d_in[0];
  const float* pq = (const float*)d_in[1];
  const float* cb = (const float*)d_in[2];
  const float* u  = (const float*)d_in[3];
  char* ws   = (char*)d_ws;
  float* out = (float*)d_out;
  gvq_prep<<<64, 256, 0, stream>>>(cb, ws);
  gvq_main<<<NBLK, NTHREADS, 0, stream>>>(z, pq, u, ws, out);
  gvq_red<<<32, 512, 0, stream>>>(ws);
  gvq_final<<<1, 256, 0, stream>>>(ws, out);
}

// Round 11
// 247.313 us; speedup vs baseline: 1.4304x; 1.4304x over previous
//
#include <hip/hip_runtime.h>

#define BS 65536
#define DIM 64
#define SD 1024
#define NTHREADS 512
#define NBLK 512          // 8 waves/block, each wave owns 16 rows, no mid-kernel barriers
#define LOG2E 1.44269504f
#define LN2   0.69314718f

// LDS layout (bytes)
#define L_PAVW   0        // [8][1024] f32 per-wave avg-prob accumulator (single-writer)
#define L_EYB    32768    // [8][16*80] ey bounce buffer (1280 B/wave, rows stride 80)
#define L_ZY     43008    // [8][16] f32 Zy per row
#define L_WRED   43520    // [8] f32
#define LDS_BYTES 43584

// workspace layout (bytes)
#define WS_CBB   0        // [1024][64] bf16 row-major codebook (128 KB)
#define WS_CBT   131072   // [64][1024] bf16 transposed codebook (128 KB)
#define WS_C2    262144   // [1024] f32
#define WS_AVG   266240   // [1024] f32 accumulator (zeroed by prep)
#define WS_APART 270336   // [512][1024] f32 per-block avg partials (2 MB)
#define WS_LPART 2367488  // [512] f32 per-block loss partials

typedef __attribute__((ext_vector_type(8))) short bf16x8;
typedef __attribute__((ext_vector_type(4))) float f32x4;

__device__ __forceinline__ unsigned short f2bf(float f) {
  union { float f; unsigned int u; } v; v.f = f;
  unsigned int r = v.u + 0x7fffu + ((v.u >> 16) & 1u);
  return (unsigned short)(r >> 16);
}
__device__ __forceinline__ float wsum64(float v) {
  #pragma unroll
  for (int m = 1; m < 64; m <<= 1) v += __shfl_xor(v, m);
  return v;
}
__device__ __forceinline__ bf16x8 pack8(float4 a, float4 b) {
  bf16x8 r;
  r[0]=(short)f2bf(a.x); r[1]=(short)f2bf(a.y); r[2]=(short)f2bf(a.z); r[3]=(short)f2bf(a.w);
  r[4]=(short)f2bf(b.x); r[5]=(short)f2bf(b.y); r[6]=(short)f2bf(b.z); r[7]=(short)f2bf(b.w);
  return r;
}

// ---------------- prep: bf16 codebook (row-major + transposed), c2, zero avgg ----------------
__global__ __launch_bounds__(256) void gvq_prep(const float* __restrict__ cb, char* __restrict__ ws) {
  int gid = blockIdx.x * 256 + threadIdx.x;   // 0..16383
  int j = gid >> 4, dg = gid & 15;
  float4 v = *(const float4*)(cb + j * DIM + dg * 4);
  float s = v.x*v.x + v.y*v.y + v.z*v.z + v.w*v.w;
  s += __shfl_xor(s, 1); s += __shfl_xor(s, 2); s += __shfl_xor(s, 4); s += __shfl_xor(s, 8);
  unsigned short b0 = f2bf(v.x), b1 = f2bf(v.y), b2 = f2bf(v.z), b3 = f2bf(v.w);
  uint2 pk;
  pk.x = (unsigned)b0 | ((unsigned)b1 << 16);
  pk.y = (unsigned)b2 | ((unsigned)b3 << 16);
  *(uint2*)(ws + WS_CBB + j * 128 + dg * 8) = pk;
  unsigned short* tb = (unsigned short*)(ws + WS_CBT);
  int d = dg * 4;
  tb[(d + 0) * 1024 + j] = b0; tb[(d + 1) * 1024 + j] = b1;
  tb[(d + 2) * 1024 + j] = b2; tb[(d + 3) * 1024 + j] = b3;
  if (dg == 0) ((float*)(ws + WS_C2))[j] = s;
  if (gid < SD) ((float*)(ws + WS_AVG))[gid] = 0.f;
}

// ---------------- main: 512 blocks x 8 independent waves x 16 rows ----------------
__global__ __launch_bounds__(NTHREADS, 2) void gvq_main(
    const float* __restrict__ z, const float* __restrict__ pq,
    const float* __restrict__ u, char* __restrict__ ws,
    float* __restrict__ out)
{
  extern __shared__ char smem[];
  const int t    = threadIdx.x;
  const int lane = t & 63;
  const int wave = t >> 6;
  const int l15  = lane & 15;
  const int g    = lane >> 4;          // 0..3

  float* pavw = (float*)(smem + L_PAVW) + wave * 1024;
  char*  eyb  = smem + L_EYB + wave * 1280;
  float* zyw  = (float*)(smem + L_ZY) + wave * 16;
  float* wred = (float*)(smem + L_WRED);

  const char*  cbbp = ws + WS_CBB;
  const char*  cbtp = ws + WS_CBT;
  const float* c2p  = (const float*)(ws + WS_C2);
  float* apart = (float*)(ws + WS_APART);
  float* lpart = (float*)(ws + WS_LPART);

  const int r0 = (blockIdx.x * 8 + wave) * 16;

  const float weight = 0.5f / fmaxf(pq[0], 1e-10f);
  const float w2  = weight * LOG2E;    // log2-domain scale
  const float w22 = 2.f * w2;

  // zero this wave's pav slice (own slice only -> no sync needed)
  #pragma unroll
  for (int i = 0; i < 16; ++i) pavw[lane + 64 * i] = 0.f;

  // ---- z fragment (B-operand layout: row=l15, k=(g*8..g*8+7) and +32) + z2 ----
  const float* zr = z + (size_t)(r0 + l15) * DIM + g * 8;
  float4 za = *(const float4*)(zr);
  float4 zb = *(const float4*)(zr + 4);
  float4 zc = *(const float4*)(zr + 32);
  float4 zd = *(const float4*)(zr + 36);
  bf16x8 zf0 = pack8(za, zb);
  bf16x8 zf1 = pack8(zc, zd);
  float zsq = za.x*za.x+za.y*za.y+za.z*za.z+za.w*za.w
            + zb.x*zb.x+zb.y*zb.y+zb.z*zb.z+zb.w*zb.w
            + zc.x*zc.x+zc.y*zc.y+zc.z*zc.z+zc.w*zc.w
            + zd.x*zd.x+zd.y*zd.y+zd.z*zd.z+zd.w*zd.w;
  zsq += __shfl_xor(zsq, 16); zsq += __shfl_xor(zsq, 32);   // z2 of row l15
  const float zpart = w2 * zsq;

#define CLD0(S) (*(const bf16x8*)(cbbp + ((S) * 16 + l15) * 128 + g * 16))
#define CLD1(S) (*(const bf16x8*)(cbbp + ((S) * 16 + l15) * 128 + g * 16 + 64))

  // ---- pass AB: online max + Zs + E1; depth-4 subtile software pipeline ----
  float m = -1e30f, Zs = 0.f, E1 = 0.f;
  {
    bf16x8 A0 = CLD0(0), A1 = CLD1(0);
    bf16x8 B0 = CLD0(1), B1 = CLD1(1);
    bf16x8 C0 = CLD0(2), C1 = CLD1(2);
    bf16x8 D0 = CLD0(3), D1 = CLD1(3);
#define ABSTEP(TT, F0, F1) do { \
      f32x4 acc = {0.f, 0.f, 0.f, 0.f}; \
      acc = __builtin_amdgcn_mfma_f32_16x16x32_bf16(F0, zf0, acc, 0, 0, 0); \
      acc = __builtin_amdgcn_mfma_f32_16x16x32_bf16(F1, zf1, acc, 0, 0, 0); \
      float4 c2v = *(const float4*)(c2p + (TT) * 16 + g * 4); \
      float s0 = fmaf(w22, acc[0], -(zpart + w2 * c2v.x)); \
      float s1 = fmaf(w22, acc[1], -(zpart + w2 * c2v.y)); \
      float s2 = fmaf(w22, acc[2], -(zpart + w2 * c2v.z)); \
      float s3 = fmaf(w22, acc[3], -(zpart + w2 * c2v.w)); \
      float nm = fmaxf(fmaxf(fmaxf(s0, s1), fmaxf(s2, s3)), m); \
      float dmx = fminf(nm - m, 60.f); \
      float sc = __builtin_amdgcn_exp2f(-dmx); \
      E1 = sc * (E1 - dmx * Zs); \
      Zs = sc * Zs; \
      m = nm; \
      float d0 = s0 - m, d1 = s1 - m, d2 = s2 - m, d3 = s3 - m; \
      float e0 = __builtin_amdgcn_exp2f(d0), e1 = __builtin_amdgcn_exp2f(d1); \
      float e2 = __builtin_amdgcn_exp2f(d2), e3 = __builtin_amdgcn_exp2f(d3); \
      Zs += (e0 + e1) + (e2 + e3); \
      E1 += (e0 * d0 + e1 * d1) + (e2 * d2 + e3 * d3); \
    } while (0)
    for (int tt = 0; tt < 64; tt += 2) {
      bf16x8 E0v, E1v, F0v, F1v;
      if (tt + 4 < 64) { E0v = CLD0(tt + 4); E1v = CLD1(tt + 4); }
      if (tt + 5 < 64) { F0v = CLD0(tt + 5); F1v = CLD1(tt + 5); }
      ABSTEP(tt, A0, A1);
      ABSTEP(tt + 1, B0, B1);
      A0 = C0; A1 = C1; B0 = D0; B1 = D1;
      C0 = E0v; C1 = E1v; D0 = F0v; D1 = F1v;
    }
#undef ABSTEP
  }
  // merge across the 4 g-groups (same row): flash-style stat merge
  #pragma unroll
  for (int mk = 16; mk < 64; mk <<= 1) {
    float mo = __shfl_xor(m, mk);
    float Zo = __shfl_xor(Zs, mk);
    float Eo = __shfl_xor(E1, mk);
    float M  = fmaxf(m, mo);
    float a  = __builtin_amdgcn_exp2f(m - M);
    float b  = __builtin_amdgcn_exp2f(mo - M);
    float Zn = a * Zs + b * Zo;
    E1 = a * (E1 - (M - m) * Zs) + b * (Eo - (M - mo) * Zo);
    Zs = Zn;
    m = M;
  }
  const float invZ = 1.f / Zs;
  float kd_acc = 0.f;
  if (g == 0) kd_acc = LN2 * (E1 * invZ - __builtin_amdgcn_logf(Zs));

  // ---- pass C: flattened subtile loop, depth-1 prefetch + early cbT loads ----
  f32x4 q[4];
  #pragma unroll
  for (int dt = 0; dt < 4; ++dt) q[dt] = (f32x4){0.f, 0.f, 0.f, 0.f};
  float Zy = 0.f;
  const float* up = u + (size_t)(r0 + l15) * SD;

  {
    bf16x8 cc0 = CLD0(0), cc1 = CLD1(0);
    float4 uu = *(const float4*)(up + g * 4);
    bf16x8 bt0, bt1, bt2, bt3;   // cbT PV frags, loaded at even s, used at odd s
    for (int s = 0; s < 64; ++s) {
      bf16x8 cn0, cn1; float4 un;
      if (s + 1 < 64) {
        cn0 = CLD0(s + 1); cn1 = CLD1(s + 1);
        un = *(const float4*)(up + (s + 1) * 16 + g * 4);
      }
      if (!(s & 1)) {  // prefetch PV B-frags for kt = s>>1 (used next iteration)
        const char* bp = cbtp + l15 * 2048 + (s >> 1) * 64 + g * 16;
        bt0 = *(const bf16x8*)(bp);
        bt1 = *(const bf16x8*)(bp + 32768);
        bt2 = *(const bf16x8*)(bp + 65536);
        bt3 = *(const bf16x8*)(bp + 98304);
      }
      f32x4 acc = {0.f, 0.f, 0.f, 0.f};
      acc = __builtin_amdgcn_mfma_f32_16x16x32_bf16(cc0, zf0, acc, 0, 0, 0);
      acc = __builtin_amdgcn_mfma_f32_16x16x32_bf16(cc1, zf1, acc, 0, 0, 0);
      float4 c2v = *(const float4*)(c2p + s * 16 + g * 4);
      float d0 = fmaf(w22, acc[0], -(zpart + w2 * c2v.x)) - m;
      float d1 = fmaf(w22, acc[1], -(zpart + w2 * c2v.y)) - m;
      float d2 = fmaf(w22, acc[2], -(zpart + w2 * c2v.z)) - m;
      float d3 = fmaf(w22, acc[3], -(zpart + w2 * c2v.w)) - m;
      float e0 = __builtin_amdgcn_exp2f(d0), e1 = __builtin_amdgcn_exp2f(d1);
      float e2 = __builtin_amdgcn_exp2f(d2), e3 = __builtin_amdgcn_exp2f(d3);
      // pav: p = e*invZ, reduce over 16 rows (l15 tree), single-writer RMW
      float p0 = e0 * invZ, p1 = e1 * invZ, p2 = e2 * invZ, p3 = e3 * invZ;
      #pragma unroll
      for (int mk = 1; mk < 16; mk <<= 1) {
        p0 += __shfl_xor(p0, mk); p1 += __shfl_xor(p1, mk);
        p2 += __shfl_xor(p2, mk); p3 += __shfl_xor(p3, mk);
      }
      if (l15 == 0) {
        float4* pp = (float4*)(pavw + s * 16 + g * 4);
        float4 pv = *pp;
        pv.x += p0; pv.y += p1; pv.z += p2; pv.w += p3;
        *pp = pv;
      }
      // gumbel: ey = e * 2^-24 / (-ln(u+eps)+eps)
      float B0 = fmaf(-LN2, __builtin_amdgcn_logf(uu.x + 1e-10f), 1e-10f);
      float B1 = fmaf(-LN2, __builtin_amdgcn_logf(uu.y + 1e-10f), 1e-10f);
      float B2 = fmaf(-LN2, __builtin_amdgcn_logf(uu.z + 1e-10f), 1e-10f);
      float B3 = fmaf(-LN2, __builtin_amdgcn_logf(uu.w + 1e-10f), 1e-10f);
      float y0 = e0 * (5.9604645e-8f * __builtin_amdgcn_rcpf(B0));
      float y1 = e1 * (5.9604645e-8f * __builtin_amdgcn_rcpf(B1));
      float y2 = e2 * (5.9604645e-8f * __builtin_amdgcn_rcpf(B2));
      float y3 = e3 * (5.9604645e-8f * __builtin_amdgcn_rcpf(B3));
      Zy += (y0 + y1) + (y2 + y3);
      uint2 pk;
      pk.x = (unsigned)f2bf(y0) | ((unsigned)f2bf(y1) << 16);
      pk.y = (unsigned)f2bf(y2) | ((unsigned)f2bf(y3) << 16);
      *(uint2*)(eyb + l15 * 80 + (s & 1) * 32 + g * 8) = pk;
      if (s & 1) {  // PV for kt = s>>1 (both halves of eyb row now written)
        bf16x8 ef = *(const bf16x8*)(eyb + l15 * 80 + g * 16);
        q[0] = __builtin_amdgcn_mfma_f32_16x16x32_bf16(ef, bt0, q[0], 0, 0, 0);
        q[1] = __builtin_amdgcn_mfma_f32_16x16x32_bf16(ef, bt1, q[1], 0, 0, 0);
        q[2] = __builtin_amdgcn_mfma_f32_16x16x32_bf16(ef, bt2, q[2], 0, 0, 0);
        q[3] = __builtin_amdgcn_mfma_f32_16x16x32_bf16(ef, bt3, q[3], 0, 0, 0);
      }
      cc0 = cn0; cc1 = cn1; uu = un;
    }
  }
#undef CLD0
#undef CLD1

  // ---- epilogue: Zy reduce, normalize, out, kc ----
  Zy += __shfl_xor(Zy, 16); Zy += __shfl_xor(Zy, 32);
  if (lane < 16) zyw[lane] = Zy;
  float kc_acc = 0.f;
  {
    float iy0 = 1.f / zyw[4 * g + 0];
    float iy1 = 1.f / zyw[4 * g + 1];
    float iy2 = 1.f / zyw[4 * g + 2];
    float iy3 = 1.f / zyw[4 * g + 3];
    #pragma unroll
    for (int dt = 0; dt < 4; ++dt) {
      int col = dt * 16 + l15;
      #pragma unroll
      for (int r = 0; r < 4; ++r) {
        float iy = (r == 0) ? iy0 : (r == 1) ? iy1 : (r == 2) ? iy2 : iy3;
        int row = r0 + 4 * g + r;
        float v = q[dt][r] * iy;
        out[(size_t)row * DIM + col] = v;
        float zv = z[(size_t)row * DIM + col];
        float dq = zv - v;
        kc_acc += dq * dq;
      }
    }
  }
  float kcs = wsum64(kc_acc);
  float kds = wsum64(kd_acc);
  if (lane == 0) wred[wave] = kds + weight * kcs;

  // ---- single block barrier, then flush partials ----
  __syncthreads();
  {
    const float* pv0 = (const float*)(smem + L_PAVW);
    float s0 = 0.f, s1 = 0.f;
    #pragma unroll
    for (int w = 0; w < 8; ++w) {
      s0 += pv0[w * 1024 + t];
      s1 += pv0[w * 1024 + t + 512];
    }
    apart[(size_t)blockIdx.x * 1024 + t]       = s0;
    apart[(size_t)blockIdx.x * 1024 + t + 512] = s1;
    if (t == 0) {
      float L = 0.f;
      #pragma unroll
      for (int w = 0; w < 8; ++w) L += wred[w];
      lpart[blockIdx.x] = L;
    }
  }
}

// ---------------- reduce avg partials: 32 blocks x 16 rows each ----------------
__global__ __launch_bounds__(512) void gvq_red(char* __restrict__ ws) {
  const float* apart = (const float*)(ws + WS_APART);
  float* avgg        = (float*)(ws + WS_AVG);
  int bb = blockIdx.x, t = threadIdx.x;
  float s0 = 0.f, s1 = 0.f;
  #pragma unroll
  for (int r = 0; r < 16; ++r) {
    float2 v = *(const float2*)(apart + (size_t)(bb * 16 + r) * 1024 + t * 2);
    s0 += v.x; s1 += v.y;
  }
  atomicAdd(&avgg[t * 2], s0);
  atomicAdd(&avgg[t * 2 + 1], s1);
}

// ---------------- final: loss + perplexity ----------------
__global__ __launch_bounds__(256) void gvq_final(const char* __restrict__ ws, float* __restrict__ out) {
  const float* avgg  = (const float*)(ws + WS_AVG);
  const float* lpart = (const float*)(ws + WS_LPART);
  int t = threadIdx.x;
  float s = 0.f;
  #pragma unroll
  for (int i = t; i < SD; i += 256) {
    float a = avgg[i] * (1.f / 65536.f);
    s += a * logf(a + 1e-7f);
  }
  float lp = lpart[t] + lpart[t + 256];
  s = wsum64(s); lp = wsum64(lp);
  __shared__ float ws1[4], ws2[4];
  if ((t & 63) == 0) { ws1[t >> 6] = s; ws2[t >> 6] = lp; }
  __syncthreads();
  if (t == 0) {
    float tot = ws1[0] + ws1[1] + ws1[2] + ws1[3];
    float L   = ws2[0] + ws2[1] + ws2[2] + ws2[3];
    out[(size_t)BS * DIM]     = L * (1.f / 65536.f);
    out[(size_t)BS * DIM + 1] = expf(-tot);
  }
}

extern "C" void kernel_launch(void* const* d_in, const int* in_sizes, int n_in,
                              void* d_out, int out_size, void* d_ws, size_t ws_size,
                              hipStream_t stream) {
  (void)in_sizes; (void)n_in; (void)out_size; (void)ws_size;
  const float* z  = (const float*)d_in[0];
  const float* pq = (const float*)d_in[1];
  const float* cb = (const float*)d_in[2];
  const float* u  = (const float*)d_in[3];
  char* ws   = (char*)d_ws;
  float* out = (float*)d_out;
  gvq_prep<<<64, 256, 0, stream>>>(cb, ws);
  gvq_main<<<NBLK, NTHREADS, LDS_BYTES, stream>>>(z, pq, u, ws, out);
  gvq_red<<<32, 512, 0, stream>>>(ws);
  gvq_final<<<1, 256, 0, stream>>>(ws, out);
}